// Round 9
// baseline (6287.983 us; speedup 1.0000x reference)
//
#include <hip/hip_runtime.h>
#include <hip/hip_bf16.h>

// Problem dims
#define BB 2
#define TT 16
#define DD 64
#define HH 64
#define WW 64
#define NPIX 131072

// ESTABLISHED (R0-R8):
//  - Inputs f32, output bf16 (uint16<<16), out_size 16,777,216 (32 MiB).
//  - R8 (inputs re<->im swapped, (re,im) pairs) -> absmax 1.09: residual-x
//    CANCELS (any misplacement forces >=7.5) => either T1 (inputs swapped,
//    (re,im) pairs, + unknown delta bug) or T2 (inputs UNswapped, pair order
//    (im,re); R8's swap made x'=i*conj(x), residual cancels, delta mismatch
//    ~1.1 = exactly observed). No delta bug found after exhaustive audit =>
//    testing T2 this round: unswapped inputs, out pairs = (im, re).
// Buffers: ws = bf16 [131072,128] ping (32 MiB) + f32 weights (~0.8 MiB);
// d_out doubles as bf16 pong (k3/k_scan safe in-place; k5 overwrites all).

typedef unsigned short u16;
typedef unsigned int u32;

__device__ __forceinline__ float us2f(u16 u) {
  union { u32 i; float f; } c; c.i = ((u32)u) << 16; return c.f;
}
__device__ __forceinline__ u16 f2us(float f) {
  u32 x = __float_as_uint(f);
  u32 r = x + 0x7fffu + ((x >> 16) & 1u);  // RNE
  return (u16)(r >> 16);
}

// ---------------------------------------------------------------------------
// Prep: conv weights f32 [o][i][3][3] -> f32 wT[tap][in][out];
// enc/dec -> f32 128x128 real-equivalent complex-mix matrices [[re,im],[-im,re]]
// ---------------------------------------------------------------------------
__global__ __launch_bounds__(256) void k0_prep(
    const float* __restrict__ conv_w,
    const float* __restrict__ enc_re, const float* __restrict__ enc_im,
    const float* __restrict__ dec_re, const float* __restrict__ dec_im,
    float* __restrict__ wT, float* __restrict__ Menc, float* __restrict__ Mdec) {
  int idx = blockIdx.x * 256 + threadIdx.x;
  if (idx < 147456) {
    int o = idx & 127, i = (idx >> 7) & 127, tap = idx >> 14;  // tap = kh*3+kw
    int kh = tap / 3, kw = tap % 3;
    wT[idx] = conv_w[((o * 128 + i) * 3 + kh) * 3 + kw];
  }
  int j = idx - 147456;
  if (j >= 0 && j < 16384) {
    int o = j & 127, dIn = j >> 7;
    float v;
    if (dIn < 64) v = (o < 64) ?  enc_re[dIn * 64 + o]        : enc_im[dIn * 64 + (o - 64)];
    else          v = (o < 64) ? -enc_im[(dIn - 64) * 64 + o] : enc_re[(dIn - 64) * 64 + (o - 64)];
    Menc[j] = v;
  }
  int k = idx - 163840;
  if (k >= 0 && k < 16384) {
    int o = k & 127, dIn = k >> 7;
    float v;
    if (dIn < 64) v = (o < 64) ?  dec_re[dIn * 64 + o]        : dec_im[dIn * 64 + (o - 64)];
    else          v = (o < 64) ? -dec_im[(dIn - 64) * 64 + o] : dec_re[(dIn - 64) * 64 + (o - 64)];
    Mdec[k] = v;
  }
}

// ---------------------------------------------------------------------------
// K1: spatial LayerNorm over channels, f32 NCHW(re|im planes) -> bf16
// channels-last. block = one (n,h) row of 64 pixels.
// ---------------------------------------------------------------------------
__global__ __launch_bounds__(256) void k1_spatial_ln(
    const float* __restrict__ x_re, const float* __restrict__ x_im,
    const float* __restrict__ g, const float* __restrict__ b,
    u16* __restrict__ xn) {
  __shared__ float tile[64 * 129];
  __shared__ float meanA[64], rstdA[64];
  int n = blockIdx.x >> 6, h = blockIdx.x & 63;
  int tid = threadIdx.x;
  for (int k = 0; k < 32; ++k) {
    int flat = tid + k * 256;
    int c = flat >> 6, w = flat & 63;
    float v = (c < 64) ? x_re[n * 262144 + c * 4096 + h * 64 + w]
                       : x_im[n * 262144 + (c - 64) * 4096 + h * 64 + w];
    tile[w * 129 + c] = v;
  }
  __syncthreads();
  int p = tid >> 2, q = tid & 3;
  float s = 0.f, ss = 0.f;
  for (int c = q * 32; c < q * 32 + 32; ++c) {
    float v = tile[p * 129 + c];
    s += v; ss += v * v;
  }
  s += __shfl_xor(s, 1); ss += __shfl_xor(ss, 1);
  s += __shfl_xor(s, 2); ss += __shfl_xor(ss, 2);
  if (q == 0) {
    float m = s * (1.0f / 128.0f);
    float var = ss * (1.0f / 128.0f) - m * m;
    meanA[p] = m; rstdA[p] = rsqrtf(var + 1e-5f);
  }
  __syncthreads();
  int rowbase = (n * 4096 + h * 64) * 128;
  for (int k = 0; k < 32; ++k) {
    int flat = tid + k * 256;
    int pp = flat >> 7, c = flat & 127;
    float v = (tile[pp * 129 + c] - meanA[pp]) * rstdA[pp] * g[c] + b[c];
    xn[rowbase + flat] = f2us(v);
  }
}

// ---------------------------------------------------------------------------
// K2: 3x3 SAME cross-correlation, channels-last bf16 in/out, f32 weights.
// ---------------------------------------------------------------------------
__global__ __launch_bounds__(256) void k2_conv(
    const u16* __restrict__ xn, const float* __restrict__ wT,
    const float* __restrict__ conv_b, u16* __restrict__ xs) {
  __shared__ float tile[64 * 129];
  int n = blockIdx.x >> 6, h = blockIdx.x & 63;
  int tid = threadIdx.x;
  int w = tid & 63, og = tid >> 6;
  float acc[32];
#pragma unroll
  for (int oc = 0; oc < 32; ++oc) acc[oc] = conv_b[og * 32 + oc];

  for (int dh = 0; dh < 3; ++dh) {
    int hs = h + dh - 1;
    if (hs < 0 || hs >= 64) continue;  // block-uniform
    __syncthreads();
    const uint4* src = (const uint4*)(xn + (n * 4096 + hs * 64) * 128);
#pragma unroll
    for (int k = 0; k < 4; ++k) {
      int f8 = tid + k * 256;
      int wp_ = f8 >> 4, c8 = f8 & 15;
      uint4 v = src[f8];
      const u16* sv = (const u16*)&v;
#pragma unroll
      for (int j = 0; j < 8; ++j) tile[wp_ * 129 + c8 * 8 + j] = us2f(sv[j]);
    }
    __syncthreads();
    const float* wbase = wT + dh * 3 * 128 * 128 + og * 32;
    for (int i = 0; i < 128; ++i) {
      float xm = (w > 0)  ? tile[(w - 1) * 129 + i] : 0.0f;
      float x0 = tile[w * 129 + i];
      float xp = (w < 63) ? tile[(w + 1) * 129 + i] : 0.0f;
#pragma unroll
      for (int kw = 0; kw < 3; ++kw) {
        float xv = (kw == 0) ? xm : ((kw == 1) ? x0 : xp);
        const float4* wp4 = (const float4*)(wbase + (kw * 128 + i) * 128);
#pragma unroll
        for (int r = 0; r < 8; ++r) {
          float4 wv = wp4[r];
          acc[r * 4 + 0] += xv * wv.x;
          acc[r * 4 + 1] += xv * wv.y;
          acc[r * 4 + 2] += xv * wv.z;
          acc[r * 4 + 3] += xv * wv.w;
        }
      }
    }
  }
  __syncthreads();
#pragma unroll
  for (int oc = 0; oc < 32; ++oc) tile[w * 129 + og * 32 + oc] = acc[oc];
  __syncthreads();
  int rowbase = (n * 4096 + h * 64) * 128;
  for (int k = 0; k < 32; ++k) {
    int flat = tid + k * 256;
    int pp = flat >> 7, c = flat & 127;
    xs[rowbase + flat] = f2us(tile[pp * 129 + c]);
  }
}

// ---------------------------------------------------------------------------
// K3: IN-PLACE bf16 [P,128] @ f32 Menc (block stages its slice first = safe).
// ---------------------------------------------------------------------------
__global__ __launch_bounds__(256) void k3_gemm128_inplace(
    u16* X, const float* __restrict__ M) {
  __shared__ float tile[64 * 129];
  int pixbase = blockIdx.x * 64;
  int tid = threadIdx.x;
  int w = tid & 63, og = tid >> 6;
  const uint4* src = (const uint4*)(X + pixbase * 128);
#pragma unroll
  for (int k = 0; k < 4; ++k) {
    int f8 = tid + k * 256;
    int p = f8 >> 4, c8 = f8 & 15;
    uint4 v = src[f8];
    const u16* sv = (const u16*)&v;
#pragma unroll
    for (int j = 0; j < 8; ++j) tile[p * 129 + c8 * 8 + j] = us2f(sv[j]);
  }
  __syncthreads();
  float acc[32];
#pragma unroll
  for (int j = 0; j < 32; ++j) acc[j] = 0.f;
  for (int d = 0; d < 128; ++d) {
    float xv = tile[w * 129 + d];
    const float4* mp = (const float4*)(M + d * 128 + og * 32);
#pragma unroll
    for (int r = 0; r < 8; ++r) {
      float4 wv = mp[r];
      acc[r * 4 + 0] += xv * wv.x;
      acc[r * 4 + 1] += xv * wv.y;
      acc[r * 4 + 2] += xv * wv.z;
      acc[r * 4 + 3] += xv * wv.w;
    }
  }
  __syncthreads();
#pragma unroll
  for (int j = 0; j < 32; ++j) tile[w * 129 + og * 32 + j] = acc[j];
  __syncthreads();
  for (int k = 0; k < 32; ++k) {
    int flat = tid + k * 256;
    int pp = flat >> 7, c = flat & 127;
    X[pixbase * 128 + flat] = f2us(tile[pp * 129 + c]);
  }
}

// ---------------------------------------------------------------------------
// K_scan: temporal ZOH scan T=16, in place on bf16 u [n=b*16+t][hw][re|im].
// ---------------------------------------------------------------------------
__global__ __launch_bounds__(256) void k_scan(
    u16* __restrict__ u, const float* __restrict__ dt,
    const float* __restrict__ alpha, const float* __restrict__ omega,
    const float* __restrict__ ns_p) {
  int flat = blockIdx.x * 256 + threadIdx.x;
  int d = flat & 63;
  int hw = (flat >> 6) & 4095;
  int b = flat >> 18;
  float a = alpha[d];
  float sp = (a > 20.f) ? a : log1pf(expf(a));
  float lr = -sp, li = omega[d];
  float inv_l2 = 1.0f / (lr * lr + li * li);
  float ns = ns_p[0];
  float yr = 0.f, yi = 0.f;
  const int stride = 4096 * 128;
  int base0 = b * 16 * stride + hw * 128 + d;
  for (int t = 0; t < 16; ++t) {
    float dtv = dt[t];
    float er = expf(lr * dtv);
    float ang = li * dtv;
    float dr = er * cosf(ang), di = er * sinf(ang);
    float fr = ((dr - 1.f) * lr + di * li) * inv_l2;
    float fi = (di * lr - (dr - 1.f) * li) * inv_l2;
    int idx = base0 + t * stride;
    float ur = us2f(u[idx]), ui = us2f(u[idx + 64]);
    float usr = ur * fr - ui * fi;
    float usi = ur * fi + ui * fr;
    float nyr = dr * yr - di * yi + usr;
    float nyi = dr * yi + di * yr + usi;
    yr = nyr; yi = nyi;
    float sc = 1.0f + ns * sqrtf(dtv);
    u[idx] = f2us(yr * sc);
    u[idx + 64] = f2us(yi * sc);
  }
}

// ---------------------------------------------------------------------------
// K4: decode GEMM (Mdec) + temporal LayerNorm, fused.
// ---------------------------------------------------------------------------
__global__ __launch_bounds__(256) void k4_decode_ln(
    const u16* __restrict__ U, const float* __restrict__ M,
    const float* __restrict__ g, const float* __restrict__ bb,
    u16* __restrict__ xo) {
  __shared__ float tile[64 * 129];
  __shared__ float psum[4 * 64], psumsq[4 * 64];
  __shared__ float meanA[64], rstdA[64];
  int pixbase = blockIdx.x * 64;
  int tid = threadIdx.x;
  int w = tid & 63, og = tid >> 6;
  const uint4* src = (const uint4*)(U + pixbase * 128);
#pragma unroll
  for (int k = 0; k < 4; ++k) {
    int f8 = tid + k * 256;
    int p = f8 >> 4, c8 = f8 & 15;
    uint4 v = src[f8];
    const u16* sv = (const u16*)&v;
#pragma unroll
    for (int j = 0; j < 8; ++j) tile[p * 129 + c8 * 8 + j] = us2f(sv[j]);
  }
  __syncthreads();
  float acc[32];
#pragma unroll
  for (int j = 0; j < 32; ++j) acc[j] = 0.f;
  for (int d = 0; d < 128; ++d) {
    float xv = tile[w * 129 + d];
    const float4* mp = (const float4*)(M + d * 128 + og * 32);
#pragma unroll
    for (int r = 0; r < 8; ++r) {
      float4 wv = mp[r];
      acc[r * 4 + 0] += xv * wv.x;
      acc[r * 4 + 1] += xv * wv.y;
      acc[r * 4 + 2] += xv * wv.z;
      acc[r * 4 + 3] += xv * wv.w;
    }
  }
  float s = 0.f, ss = 0.f;
#pragma unroll
  for (int j = 0; j < 32; ++j) { s += acc[j]; ss += acc[j] * acc[j]; }
  psum[og * 64 + w] = s;
  psumsq[og * 64 + w] = ss;
  __syncthreads();
  if (tid < 64) {
    float S = psum[tid] + psum[64 + tid] + psum[128 + tid] + psum[192 + tid];
    float SS = psumsq[tid] + psumsq[64 + tid] + psumsq[128 + tid] + psumsq[192 + tid];
    float m = S * (1.0f / 128.0f);
    float var = SS * (1.0f / 128.0f) - m * m;
    meanA[tid] = m; rstdA[tid] = rsqrtf(var + 1e-5f);
  }
  __syncthreads();
  float m = meanA[w], r = rstdA[w];
#pragma unroll
  for (int j = 0; j < 32; ++j) {
    int c = og * 32 + j;
    tile[w * 129 + c] = (acc[j] - m) * r * g[c] + bb[c];
  }
  __syncthreads();
  for (int k = 0; k < 32; ++k) {
    int flat = tid + k * 256;
    int pp = flat >> 7, c = flat & 127;
    xo[pixbase * 128 + flat] = f2us(tile[pp * 129 + c]);
  }
}

// ---------------------------------------------------------------------------
// K5: soft MoE + residual (f32 x), scatter to (IM, RE) bf16 pairs per
// complex element (T2 layout). block = 32 pixels.
// ---------------------------------------------------------------------------
__global__ __launch_bounds__(256) void k5_moe(
    const u16* __restrict__ xo, const float* __restrict__ w_router,
    const float* __restrict__ w1, const float* __restrict__ w2,
    const float* __restrict__ x_re, const float* __restrict__ x_im,
    u16* __restrict__ out) {
  __shared__ float xin[32 * 129];
  __shared__ float hbuf[32 * 257];
  __shared__ float gate_s[32 * 4];
  int pixbase = blockIdx.x * 32;
  int tid = threadIdx.x;
  const uint4* src = (const uint4*)(xo + pixbase * 128);
#pragma unroll
  for (int k = 0; k < 2; ++k) {
    int f8 = tid + k * 256;
    int p = f8 >> 4, c8 = f8 & 15;
    uint4 v = src[f8];
    const u16* sv = (const u16*)&v;
#pragma unroll
    for (int j = 0; j < 8; ++j) xin[p * 129 + c8 * 8 + j] = us2f(sv[j]);
  }
  __syncthreads();
  if (tid < 32) {
    int p = tid;
    float l0 = 0, l1 = 0, l2 = 0, l3 = 0;
    const float4* wr = (const float4*)w_router;
    for (int c = 0; c < 128; ++c) {
      float xv = xin[p * 129 + c];
      float4 wv = wr[c];
      l0 += xv * wv.x; l1 += xv * wv.y; l2 += xv * wv.z; l3 += xv * wv.w;
    }
    float mx = fmaxf(fmaxf(l0, l1), fmaxf(l2, l3));
    float e0 = expf(l0 - mx), e1 = expf(l1 - mx), e2 = expf(l2 - mx), e3 = expf(l3 - mx);
    float inv = 1.0f / (e0 + e1 + e2 + e3);
    gate_s[p * 4 + 0] = e0 * inv; gate_s[p * 4 + 1] = e1 * inv;
    gate_s[p * 4 + 2] = e2 * inv; gate_s[p * 4 + 3] = e3 * inv;
  }
  __syncthreads();
  int pix = tid & 31, grp = tid >> 5;
  float accO[16];
#pragma unroll
  for (int o = 0; o < 16; ++o) accO[o] = 0.f;
  for (int e = 0; e < 4; ++e) {
    float acc1[32];
#pragma unroll
    for (int j = 0; j < 32; ++j) acc1[j] = 0.f;
    const float* w1b = w1 + e * 128 * 256 + grp * 32;
    for (int c = 0; c < 128; ++c) {
      float xv = xin[pix * 129 + c];
      const float4* wp = (const float4*)(w1b + c * 256);
#pragma unroll
      for (int r = 0; r < 8; ++r) {
        float4 wv = wp[r];
        acc1[r * 4 + 0] += xv * wv.x;
        acc1[r * 4 + 1] += xv * wv.y;
        acc1[r * 4 + 2] += xv * wv.z;
        acc1[r * 4 + 3] += xv * wv.w;
      }
    }
#pragma unroll
    for (int j = 0; j < 32; ++j) {
      float v = acc1[j];
      float t = 0.7978845608f * (v + 0.044715f * v * v * v);
      hbuf[pix * 257 + grp * 32 + j] = 0.5f * v * (1.0f + tanhf(t));
    }
    __syncthreads();
    float acc2[16];
#pragma unroll
    for (int o = 0; o < 16; ++o) acc2[o] = 0.f;
    const float* w2b = w2 + e * 256 * 128 + grp * 16;
    for (int j2 = 0; j2 < 256; ++j2) {
      float hv = hbuf[pix * 257 + j2];
      const float4* wp = (const float4*)(w2b + j2 * 128);
#pragma unroll
      for (int r = 0; r < 4; ++r) {
        float4 wv = wp[r];
        acc2[r * 4 + 0] += hv * wv.x;
        acc2[r * 4 + 1] += hv * wv.y;
        acc2[r * 4 + 2] += hv * wv.z;
        acc2[r * 4 + 3] += hv * wv.w;
      }
    }
    float gv = gate_s[pix * 4 + e];
#pragma unroll
    for (int o = 0; o < 16; ++o) accO[o] += gv * acc2[o];
    __syncthreads();
  }
#pragma unroll
  for (int o = 0; o < 16; ++o) xin[pix * 129 + grp * 16 + o] = accO[o];
  __syncthreads();
  for (int k = 0; k < 8; ++k) {
    int flat = tid + k * 256;
    int p = flat & 31, d = flat >> 5;
    float re = xin[p * 129 + d];
    float im = xin[p * 129 + d + 64];
    int Pp = pixbase + p;
    int n = Pp >> 12, hw = Pp & 4095;
    int gidx = (n * 64 + d) * 4096 + hw;       // [B,T,D,H,W] flat complex idx
    float rr = x_re[gidx] + re;
    float ii = x_im[gidx] + im;
    // T2 layout: pair = (im, re) -> low half im, high half re
    u32 packed = (u32)f2us(ii) | ((u32)f2us(rr) << 16);
    ((u32*)out)[gidx] = packed;
  }
}

// ---------------------------------------------------------------------------
extern "C" void kernel_launch(void* const* d_in, const int* in_sizes, int n_in,
                              void* d_out, int out_size, void* d_ws, size_t ws_size,
                              hipStream_t stream) {
  const float* x_re     = (const float*)d_in[0];   // unswapped (T2)
  const float* x_im     = (const float*)d_in[1];
  const float* dt       = (const float*)d_in[2];
  const float* ln_s_g   = (const float*)d_in[3];
  const float* ln_s_b   = (const float*)d_in[4];
  const float* conv_w   = (const float*)d_in[5];
  const float* conv_b   = (const float*)d_in[6];
  const float* ln_t_g   = (const float*)d_in[7];
  const float* ln_t_b   = (const float*)d_in[8];
  const float* enc_re   = (const float*)d_in[9];
  const float* enc_im   = (const float*)d_in[10];
  const float* dec_re   = (const float*)d_in[11];
  const float* dec_im   = (const float*)d_in[12];
  const float* alpha    = (const float*)d_in[13];
  const float* omega    = (const float*)d_in[14];
  // 15..20: wg, bg, p_re, p_im, w_drift, b_drift -> dead code in reference
  const float* w_router = (const float*)d_in[21];
  const float* w1       = (const float*)d_in[22];
  const float* w2       = (const float*)d_in[23];
  const float* ns       = (const float*)d_in[24];

  u16*   buf  = (u16*)d_ws;                              // 32 MiB bf16 ping
  float* wT   = (float*)((char*)d_ws + 33554432);        // 147,456 f32
  float* Menc = wT + 147456;                             // 16,384 f32
  float* Mdec = Menc + 16384;                            // 16,384 f32
  u16*   outf = (u16*)d_out;                             // 32 MiB bf16 pong

  k0_prep<<<704, 256, 0, stream>>>(conv_w, enc_re, enc_im, dec_re, dec_im, wT, Menc, Mdec);
  k1_spatial_ln<<<2048, 256, 0, stream>>>(x_re, x_im, ln_s_g, ln_s_b, buf);
  k2_conv<<<2048, 256, 0, stream>>>(buf, wT, conv_b, outf);
  k3_gemm128_inplace<<<2048, 256, 0, stream>>>(outf, Menc);
  k_scan<<<2048, 256, 0, stream>>>(outf, dt, alpha, omega, ns);
  k4_decode_ln<<<2048, 256, 0, stream>>>(outf, Mdec, ln_t_g, ln_t_b, buf);
  k5_moe<<<4096, 256, 0, stream>>>(buf, w_router, w1, w2, x_re, x_im, outf);
}

// Round 10
// 1325.555 us; speedup vs baseline: 4.7437x; 4.7437x over previous
//
#include <hip/hip_runtime.h>
#include <hip/hip_bf16.h>

// Problem dims
#define BB 2
#define TT 16
#define DD 64
#define HH 64
#define WW 64
#define NPIX 131072

// ESTABLISHED (R0-R9, R9 PASSED @ 6288us, absmax 0.0625):
//  - Inputs f32; output bf16 pairs per complex element, LOW half = IM,
//    HIGH half = RE, at u32 index gidx over [B,T,D,H,W].
//  - R9 rocprof: k5_moe 3810us, MfmaUtil=0, VALUBusy=16% -> latency-bound
//    scalar FMA. This round: k2 conv + k5 MoE on bf16 MFMA 16x16x32.
//  - Fragment layouts (HW-verified, learn_hip m89/m91/m120):
//    A: m=lane&15, k=(lane>>4)*8+j ; B: n=lane&15, k=(lane>>4)*8+j ;
//    C/D: col=lane&15, row=(lane>>4)*4+reg.
// ws: 32 MiB bf16 ping + Menc/Mdec f32 + swizzled bf16 weights (~33 MiB).

typedef unsigned short u16;
typedef unsigned int u32;
typedef __attribute__((ext_vector_type(8))) short bf16x8;
typedef __attribute__((ext_vector_type(4))) float f32x4;

union U16x8 { uint4 u4; uint2 u2[2]; u16 h[8]; bf16x8 v; };

__device__ __forceinline__ float us2f(u16 u) {
  union { u32 i; float f; } c; c.i = ((u32)u) << 16; return c.f;
}
__device__ __forceinline__ u16 f2us(float f) {
  u32 x = __float_as_uint(f);
  u32 r = x + 0x7fffu + ((x >> 16) & 1u);  // RNE
  return (u16)(r >> 16);
}

// ---------------------------------------------------------------------------
// Prep: Menc/Mdec f32 complex-mix matrices; bf16 fragment-swizzled weights:
//  wcs [tap9][nt8][ks4][lane64][8]  (conv: ic=ks*32+(l>>4)*8+j, oc=nt*16+(l&15))
//  w1s [e4][nt16][ks4][lane64][8]   (k -> 256-col n)
//  w2s [e4][nt8][ks8][lane64][8]    (256-k -> 128-col n)
// ---------------------------------------------------------------------------
__global__ __launch_bounds__(256) void k0_prep(
    const float* __restrict__ conv_w,
    const float* __restrict__ enc_re, const float* __restrict__ enc_im,
    const float* __restrict__ dec_re, const float* __restrict__ dec_im,
    const float* __restrict__ w1, const float* __restrict__ w2,
    float* __restrict__ Menc, float* __restrict__ Mdec,
    u16* __restrict__ wcs, u16* __restrict__ w1s, u16* __restrict__ w2s) {
  int idx = blockIdx.x * 256 + threadIdx.x;
  if (idx < 16384) {
    int o = idx & 127, dIn = idx >> 7;
    float v;
    if (dIn < 64) v = (o < 64) ?  enc_re[dIn*64+o]        : enc_im[dIn*64+o-64];
    else          v = (o < 64) ? -enc_im[(dIn-64)*64+o]   : enc_re[(dIn-64)*64+o-64];
    Menc[idx] = v;
  } else if (idx < 32768) {
    int k = idx - 16384;
    int o = k & 127, dIn = k >> 7;
    float v;
    if (dIn < 64) v = (o < 64) ?  dec_re[dIn*64+o]        : dec_im[dIn*64+o-64];
    else          v = (o < 64) ? -dec_im[(dIn-64)*64+o]   : dec_re[(dIn-64)*64+o-64];
    Mdec[k] = v;
  } else if (idx < 180224) {
    int z = idx - 32768;
    int j = z & 7, lane = (z >> 3) & 63, ks = (z >> 9) & 3, nt = (z >> 11) & 7, tap = z >> 14;
    int ic = ks * 32 + (lane >> 4) * 8 + j;
    int oc = nt * 16 + (lane & 15);
    wcs[z] = f2us(conv_w[(oc * 128 + ic) * 9 + tap]);
  } else if (idx < 311296) {
    int z = idx - 180224;
    int j = z & 7, lane = (z >> 3) & 63, ks = (z >> 9) & 3, nt = (z >> 11) & 15, e = z >> 15;
    int k = ks * 32 + (lane >> 4) * 8 + j;
    int nn = nt * 16 + (lane & 15);
    w1s[z] = f2us(w1[e * 32768 + k * 256 + nn]);
  } else if (idx < 442368) {
    int z = idx - 311296;
    int j = z & 7, lane = (z >> 3) & 63, ks = (z >> 9) & 7, nt = (z >> 12) & 7, e = z >> 15;
    int k = ks * 32 + (lane >> 4) * 8 + j;
    int nn = nt * 16 + (lane & 15);
    w2s[z] = f2us(w2[e * 32768 + k * 128 + nn]);
  }
}

// ---------------------------------------------------------------------------
// K1: spatial LayerNorm over channels, f32 NCHW(re|im planes) -> bf16
// channels-last. (unchanged from verified R9)
// ---------------------------------------------------------------------------
__global__ __launch_bounds__(256) void k1_spatial_ln(
    const float* __restrict__ x_re, const float* __restrict__ x_im,
    const float* __restrict__ g, const float* __restrict__ b,
    u16* __restrict__ xn) {
  __shared__ float tile[64 * 129];
  __shared__ float meanA[64], rstdA[64];
  int n = blockIdx.x >> 6, h = blockIdx.x & 63;
  int tid = threadIdx.x;
  for (int k = 0; k < 32; ++k) {
    int flat = tid + k * 256;
    int c = flat >> 6, w = flat & 63;
    float v = (c < 64) ? x_re[n * 262144 + c * 4096 + h * 64 + w]
                       : x_im[n * 262144 + (c - 64) * 4096 + h * 64 + w];
    tile[w * 129 + c] = v;
  }
  __syncthreads();
  int p = tid >> 2, q = tid & 3;
  float s = 0.f, ss = 0.f;
  for (int c = q * 32; c < q * 32 + 32; ++c) {
    float v = tile[p * 129 + c];
    s += v; ss += v * v;
  }
  s += __shfl_xor(s, 1); ss += __shfl_xor(ss, 1);
  s += __shfl_xor(s, 2); ss += __shfl_xor(ss, 2);
  if (q == 0) {
    float m = s * (1.0f / 128.0f);
    float var = ss * (1.0f / 128.0f) - m * m;
    meanA[p] = m; rstdA[p] = rsqrtf(var + 1e-5f);
  }
  __syncthreads();
  int rowbase = (n * 4096 + h * 64) * 128;
  for (int k = 0; k < 32; ++k) {
    int flat = tid + k * 256;
    int pp = flat >> 7, c = flat & 127;
    float v = (tile[pp * 129 + c] - meanA[pp]) * rstdA[pp] * g[c] + b[c];
    xn[rowbase + flat] = f2us(v);
  }
}

// ---------------------------------------------------------------------------
// K2 (MFMA): 3x3 SAME conv. Block = one (n,h) row of 64 px, 4 waves (wave=mt).
// LDS: 3 halo rows channels-last, row pad 132 bf16 (~2-way read alias).
// 9 taps x 8 nt x 4 ks MFMA; weights read as coalesced pre-swizzled frags.
// ---------------------------------------------------------------------------
__global__ __launch_bounds__(256) void k2_mfma(
    const u16* __restrict__ xn, const u16* __restrict__ wcs,
    const float* __restrict__ conv_b, u16* __restrict__ xs) {
  __shared__ __align__(16) u16 Xs[3 * 66 * 132];
  int tid = threadIdx.x;
  int wave = tid >> 6, lane = tid & 63;
  int quad = lane >> 4, am = lane & 15;
  int n = blockIdx.x >> 6, h = blockIdx.x & 63;

  for (int dh = 0; dh < 3; ++dh) {
    int hs = h + dh - 1;
    bool valid = (hs >= 0) && (hs < 64);
    const u16* src = xn + (n * 4096 + hs * 64) * 128;
    for (int c = 0; c < 4; ++c) {
      int f8 = tid + c * 256;            // 1024 chunks of 8 bf16
      int px = f8 >> 4, ch = (f8 & 15) * 8;
      uint2 lo = make_uint2(0, 0), hi = make_uint2(0, 0);
      if (valid) {
        const uint2* s2 = (const uint2*)(src + px * 128 + ch);
        lo = s2[0]; hi = s2[1];
      }
      u16* dst = Xs + (dh * 66 + px + 1) * 132 + ch;
      *(uint2*)dst = lo;
      *(uint2*)(dst + 4) = hi;
    }
  }
  for (int z = tid; z < 792; z += 256) {   // zero px=-1 / px=64 halos
    int dh = z / 264, r = z % 264;
    int px = (r < 132) ? 0 : 65;
    Xs[(dh * 66 + px) * 132 + (r % 132)] = 0;
  }
  __syncthreads();

  f32x4 acc[8];
#pragma unroll
  for (int nt = 0; nt < 8; ++nt) {
    float bv = conv_b[nt * 16 + am];
    acc[nt] = (f32x4){bv, bv, bv, bv};
  }
  int mt = wave;
  for (int tap = 0; tap < 9; ++tap) {
    int dh = tap / 3, dw = tap % 3;      // dw: 0,1,2 -> shift -1,0,+1 (halo idx)
    const u16* arow = Xs + (dh * 66 + mt * 16 + am + dw) * 132 + quad * 8;
    bf16x8 a[4];
#pragma unroll
    for (int ks = 0; ks < 4; ++ks) {
      U16x8 t;
      t.u2[0] = *(const uint2*)(arow + ks * 32);
      t.u2[1] = *(const uint2*)(arow + ks * 32 + 4);
      a[ks] = t.v;
    }
    const uint4* wp = (const uint4*)wcs + tap * 2048 + lane;
    for (int nt = 0; nt < 8; ++nt) {
#pragma unroll
      for (int ks = 0; ks < 4; ++ks) {
        U16x8 bf; bf.u4 = wp[(nt * 4 + ks) * 64];
        acc[nt] = __builtin_amdgcn_mfma_f32_16x16x32_bf16(a[ks], bf.v, acc[nt], 0, 0, 0);
      }
    }
  }
  int rowg = n * 4096 + h * 64;
#pragma unroll
  for (int nt = 0; nt < 8; ++nt)
#pragma unroll
    for (int r = 0; r < 4; ++r)
      xs[(rowg + mt * 16 + quad * 4 + r) * 128 + nt * 16 + am] = f2us(acc[nt][r]);
}

// ---------------------------------------------------------------------------
// K3: IN-PLACE bf16 [P,128] @ f32 Menc (unchanged from verified R9).
// ---------------------------------------------------------------------------
__global__ __launch_bounds__(256) void k3_gemm128_inplace(
    u16* X, const float* __restrict__ M) {
  __shared__ float tile[64 * 129];
  int pixbase = blockIdx.x * 64;
  int tid = threadIdx.x;
  int w = tid & 63, og = tid >> 6;
  const uint4* src = (const uint4*)(X + pixbase * 128);
#pragma unroll
  for (int k = 0; k < 4; ++k) {
    int f8 = tid + k * 256;
    int p = f8 >> 4, c8 = f8 & 15;
    uint4 v = src[f8];
    const u16* sv = (const u16*)&v;
#pragma unroll
    for (int j = 0; j < 8; ++j) tile[p * 129 + c8 * 8 + j] = us2f(sv[j]);
  }
  __syncthreads();
  float acc[32];
#pragma unroll
  for (int j = 0; j < 32; ++j) acc[j] = 0.f;
  for (int d = 0; d < 128; ++d) {
    float xv = tile[w * 129 + d];
    const float4* mp = (const float4*)(M + d * 128 + og * 32);
#pragma unroll
    for (int r = 0; r < 8; ++r) {
      float4 wv = mp[r];
      acc[r * 4 + 0] += xv * wv.x;
      acc[r * 4 + 1] += xv * wv.y;
      acc[r * 4 + 2] += xv * wv.z;
      acc[r * 4 + 3] += xv * wv.w;
    }
  }
  __syncthreads();
#pragma unroll
  for (int j = 0; j < 32; ++j) tile[w * 129 + og * 32 + j] = acc[j];
  __syncthreads();
  for (int k = 0; k < 32; ++k) {
    int flat = tid + k * 256;
    int pp = flat >> 7, c = flat & 127;
    X[pixbase * 128 + flat] = f2us(tile[pp * 129 + c]);
  }
}

// ---------------------------------------------------------------------------
// K_scan: temporal ZOH scan T=16, in place (unchanged from verified R9).
// ---------------------------------------------------------------------------
__global__ __launch_bounds__(256) void k_scan(
    u16* __restrict__ u, const float* __restrict__ dt,
    const float* __restrict__ alpha, const float* __restrict__ omega,
    const float* __restrict__ ns_p) {
  int flat = blockIdx.x * 256 + threadIdx.x;
  int d = flat & 63;
  int hw = (flat >> 6) & 4095;
  int b = flat >> 18;
  float a = alpha[d];
  float sp = (a > 20.f) ? a : log1pf(expf(a));
  float lr = -sp, li = omega[d];
  float inv_l2 = 1.0f / (lr * lr + li * li);
  float ns = ns_p[0];
  float yr = 0.f, yi = 0.f;
  const int stride = 4096 * 128;
  int base0 = b * 16 * stride + hw * 128 + d;
  for (int t = 0; t < 16; ++t) {
    float dtv = dt[t];
    float er = expf(lr * dtv);
    float ang = li * dtv;
    float dr = er * cosf(ang), di = er * sinf(ang);
    float fr = ((dr - 1.f) * lr + di * li) * inv_l2;
    float fi = (di * lr - (dr - 1.f) * li) * inv_l2;
    int idx = base0 + t * stride;
    float ur = us2f(u[idx]), ui = us2f(u[idx + 64]);
    float usr = ur * fr - ui * fi;
    float usi = ur * fi + ui * fr;
    float nyr = dr * yr - di * yi + usr;
    float nyi = dr * yi + di * yr + usi;
    yr = nyr; yi = nyi;
    float sc = 1.0f + ns * sqrtf(dtv);
    u[idx] = f2us(yr * sc);
    u[idx + 64] = f2us(yi * sc);
  }
}

// ---------------------------------------------------------------------------
// K4: decode GEMM (Mdec) + temporal LayerNorm (unchanged from verified R9).
// ---------------------------------------------------------------------------
__global__ __launch_bounds__(256) void k4_decode_ln(
    const u16* __restrict__ U, const float* __restrict__ M,
    const float* __restrict__ g, const float* __restrict__ bb,
    u16* __restrict__ xo) {
  __shared__ float tile[64 * 129];
  __shared__ float psum[4 * 64], psumsq[4 * 64];
  __shared__ float meanA[64], rstdA[64];
  int pixbase = blockIdx.x * 64;
  int tid = threadIdx.x;
  int w = tid & 63, og = tid >> 6;
  const uint4* src = (const uint4*)(U + pixbase * 128);
#pragma unroll
  for (int k = 0; k < 4; ++k) {
    int f8 = tid + k * 256;
    int p = f8 >> 4, c8 = f8 & 15;
    uint4 v = src[f8];
    const u16* sv = (const u16*)&v;
#pragma unroll
    for (int j = 0; j < 8; ++j) tile[p * 129 + c8 * 8 + j] = us2f(sv[j]);
  }
  __syncthreads();
  float acc[32];
#pragma unroll
  for (int j = 0; j < 32; ++j) acc[j] = 0.f;
  for (int d = 0; d < 128; ++d) {
    float xv = tile[w * 129 + d];
    const float4* mp = (const float4*)(M + d * 128 + og * 32);
#pragma unroll
    for (int r = 0; r < 8; ++r) {
      float4 wv = mp[r];
      acc[r * 4 + 0] += xv * wv.x;
      acc[r * 4 + 1] += xv * wv.y;
      acc[r * 4 + 2] += xv * wv.z;
      acc[r * 4 + 3] += xv * wv.w;
    }
  }
  float s = 0.f, ss = 0.f;
#pragma unroll
  for (int j = 0; j < 32; ++j) { s += acc[j]; ss += acc[j] * acc[j]; }
  psum[og * 64 + w] = s;
  psumsq[og * 64 + w] = ss;
  __syncthreads();
  if (tid < 64) {
    float S = psum[tid] + psum[64 + tid] + psum[128 + tid] + psum[192 + tid];
    float SS = psumsq[tid] + psumsq[64 + tid] + psumsq[128 + tid] + psumsq[192 + tid];
    float m = S * (1.0f / 128.0f);
    float var = SS * (1.0f / 128.0f) - m * m;
    meanA[tid] = m; rstdA[tid] = rsqrtf(var + 1e-5f);
  }
  __syncthreads();
  float m = meanA[w], r = rstdA[w];
#pragma unroll
  for (int j = 0; j < 32; ++j) {
    int c = og * 32 + j;
    tile[w * 129 + c] = (acc[j] - m) * r * g[c] + bb[c];
  }
  __syncthreads();
  for (int k = 0; k < 32; ++k) {
    int flat = tid + k * 256;
    int pp = flat >> 7, c = flat & 127;
    xo[pixbase * 128 + flat] = f2us(tile[pp * 129 + c]);
  }
}

// ---------------------------------------------------------------------------
// K5 (MFMA): soft MoE + residual. Block = 64 px, 4 waves, wave owns 16 rows.
// H (gelu intermediate) wave-private LDS (row 276 bf16: conflict-free C-writes,
// ~2-way A-reads). Weights via pre-swizzled coalesced fragments. No barriers.
// Out: LOW=im, HIGH=re u32 pack at gidx (verified T2 layout).
// ---------------------------------------------------------------------------
__global__ __launch_bounds__(256) void k5_mfma(
    const u16* __restrict__ xo, const u16* __restrict__ w1s,
    const u16* __restrict__ w2s, const float* __restrict__ w_router,
    const float* __restrict__ x_re, const float* __restrict__ x_im,
    u16* __restrict__ out) {
  __shared__ __align__(16) u16 Hs[64 * 276];
  __shared__ float gate_s[64 * 4];
  int tid = threadIdx.x;
  int wave = tid >> 6, lane = tid & 63;
  int quad = lane >> 4, am = lane & 15;
  int rowbase = blockIdx.x * 64 + wave * 16;

  // router gates (wave-private): lane -> (px=am, e=quad); shuffle softmax
  {
    int px = rowbase + am;
    const uint4* xr = (const uint4*)(xo + px * 128);
    float acc = 0.f;
    for (int c8 = 0; c8 < 16; ++c8) {
      U16x8 t; t.u4 = xr[c8];
#pragma unroll
      for (int j = 0; j < 8; ++j)
        acc += us2f(t.h[j]) * w_router[(c8 * 8 + j) * 4 + quad];
    }
    float mx = fmaxf(acc, __shfl_xor(acc, 16));
    mx = fmaxf(mx, __shfl_xor(mx, 32));
    float ex = expf(acc - mx);
    float sm = ex + __shfl_xor(ex, 16);
    sm += __shfl_xor(sm, 32);
    gate_s[(wave * 16 + am) * 4 + quad] = ex / sm;
  }

  // A-frags of X (constant across experts)
  bf16x8 ax[4];
  {
    const uint4* ar = (const uint4*)(xo + (rowbase + am) * 128 + quad * 8);
#pragma unroll
    for (int ks = 0; ks < 4; ++ks) { U16x8 t; t.u4 = ar[ks * 4]; ax[ks] = t.v; }
  }

  f32x4 accO[8];
#pragma unroll
  for (int nt = 0; nt < 8; ++nt) accO[nt] = (f32x4){0.f, 0.f, 0.f, 0.f};

  for (int e = 0; e < 4; ++e) {
    // stage a: H = gelu(X @ W1[e])  [16 px x 256 hid per wave]
    f32x4 c1[16];
#pragma unroll
    for (int nt = 0; nt < 16; ++nt) c1[nt] = (f32x4){0.f, 0.f, 0.f, 0.f};
    const uint4* w1p = (const uint4*)w1s + e * 4096 + lane;
    for (int nt = 0; nt < 16; ++nt) {
#pragma unroll
      for (int ks = 0; ks < 4; ++ks) {
        U16x8 bf; bf.u4 = w1p[(nt * 4 + ks) * 64];
        c1[nt] = __builtin_amdgcn_mfma_f32_16x16x32_bf16(ax[ks], bf.v, c1[nt], 0, 0, 0);
      }
    }
#pragma unroll
    for (int nt = 0; nt < 16; ++nt) {
#pragma unroll
      for (int r = 0; r < 4; ++r) {
        float v = c1[nt][r];
        float t = 0.7978845608f * (v + 0.044715f * v * v * v);
        float g = 0.5f * v * (1.0f + tanhf(t));
        Hs[(wave * 16 + quad * 4 + r) * 276 + nt * 16 + am] = f2us(g);
      }
    }
    // stage b: D2 = H @ W2[e]  [16 px x 128 out per wave]
    f32x4 c2[8];
#pragma unroll
    for (int nt = 0; nt < 8; ++nt) c2[nt] = (f32x4){0.f, 0.f, 0.f, 0.f};
    const uint4* w2p = (const uint4*)w2s + e * 4096 + lane;
    for (int ks = 0; ks < 8; ++ks) {
      U16x8 a2;
      const u16* hr = Hs + (wave * 16 + am) * 276 + ks * 32 + quad * 8;
      a2.u2[0] = *(const uint2*)hr;
      a2.u2[1] = *(const uint2*)(hr + 4);
#pragma unroll
      for (int nt = 0; nt < 8; ++nt) {
        U16x8 bf; bf.u4 = w2p[(nt * 8 + ks) * 64];
        c2[nt] = __builtin_amdgcn_mfma_f32_16x16x32_bf16(a2.v, bf.v, c2[nt], 0, 0, 0);
      }
    }
    float g[4];
#pragma unroll
    for (int r = 0; r < 4; ++r) g[r] = gate_s[(wave * 16 + quad * 4 + r) * 4 + e];
#pragma unroll
    for (int nt = 0; nt < 8; ++nt)
#pragma unroll
      for (int r = 0; r < 4; ++r) accO[nt][r] += g[r] * c2[nt][r];
  }

  // residual + store: same lane holds re (nt) and im (nt+4) of channel d
#pragma unroll
  for (int nt = 0; nt < 4; ++nt) {
#pragma unroll
    for (int r = 0; r < 4; ++r) {
      int px = rowbase + quad * 4 + r;
      int d = nt * 16 + am;
      int n = px >> 12, hw = px & 4095;
      int gidx = (n * 64 + d) * 4096 + hw;
      float rr = x_re[gidx] + accO[nt][r];
      float ii = x_im[gidx] + accO[nt + 4][r];
      ((u32*)out)[gidx] = (u32)f2us(ii) | ((u32)f2us(rr) << 16);
    }
  }
}

// ---------------------------------------------------------------------------
extern "C" void kernel_launch(void* const* d_in, const int* in_sizes, int n_in,
                              void* d_out, int out_size, void* d_ws, size_t ws_size,
                              hipStream_t stream) {
  const float* x_re     = (const float*)d_in[0];
  const float* x_im     = (const float*)d_in[1];
  const float* dt       = (const float*)d_in[2];
  const float* ln_s_g   = (const float*)d_in[3];
  const float* ln_s_b   = (const float*)d_in[4];
  const float* conv_w   = (const float*)d_in[5];
  const float* conv_b   = (const float*)d_in[6];
  const float* ln_t_g   = (const float*)d_in[7];
  const float* ln_t_b   = (const float*)d_in[8];
  const float* enc_re   = (const float*)d_in[9];
  const float* enc_im   = (const float*)d_in[10];
  const float* dec_re   = (const float*)d_in[11];
  const float* dec_im   = (const float*)d_in[12];
  const float* alpha    = (const float*)d_in[13];
  const float* omega    = (const float*)d_in[14];
  // 15..20: wg, bg, p_re, p_im, w_drift, b_drift -> dead code in reference
  const float* w_router = (const float*)d_in[21];
  const float* w1       = (const float*)d_in[22];
  const float* w2       = (const float*)d_in[23];
  const float* ns       = (const float*)d_in[24];

  u16*   buf  = (u16*)d_ws;                              // 32 MiB bf16 ping
  float* Menc = (float*)((char*)d_ws + 33554432);        // 16,384 f32
  float* Mdec = Menc + 16384;                            // 16,384 f32
  u16*   wcs  = (u16*)(Mdec + 16384);                    // 147,456 bf16
  u16*   w1s  = wcs + 147456;                            // 131,072 bf16
  u16*   w2s  = w1s + 131072;                            // 131,072 bf16 (~33 MiB)
  u16*   outf = (u16*)d_out;                             // 32 MiB bf16 pong

  k0_prep<<<1728, 256, 0, stream>>>(conv_w, enc_re, enc_im, dec_re, dec_im,
                                    w1, w2, Menc, Mdec, wcs, w1s, w2s);
  k1_spatial_ln<<<2048, 256, 0, stream>>>(x_re, x_im, ln_s_g, ln_s_b, buf);
  k2_mfma<<<2048, 256, 0, stream>>>(buf, wcs, conv_b, outf);
  k3_gemm128_inplace<<<2048, 256, 0, stream>>>(outf, Menc);
  k_scan<<<2048, 256, 0, stream>>>(outf, dt, alpha, omega, ns);
  k4_decode_ln<<<2048, 256, 0, stream>>>(outf, Mdec, ln_t_g, ln_t_b, buf);
  k5_mfma<<<2048, 256, 0, stream>>>(buf, w1s, w2s, w_router, x_re, x_im, outf);
}